// Round 1
// baseline (395.940 us; speedup 1.0000x reference)
//
#include <hip/hip_runtime.h>
#include <math.h>

// Problem sizes (fixed by reference setup_inputs)
constexpr int B = 64;
constexpr int S = 1024;
constexpr int H = 1024;
constexpr int L = 3;
#define NEPS 1e-12f

__device__ __forceinline__ float wave_reduce_sum(float v) {
    #pragma unroll
    for (int off = 32; off > 0; off >>= 1) v += __shfl_xor(v, off);
    return v;
}
__device__ __forceinline__ float wave_reduce_max(float v) {
    #pragma unroll
    for (int off = 32; off > 0; off >>= 1) v = fmaxf(v, __shfl_xor(v, off));
    return v;
}

// ---------------------------------------------------------------------------
// Kernel 1: normalize label embeddings over H (dim 0), store transposed
// leT[l][h] = le[h][l] / max(||le[:,l]||, eps).  One block.
// ---------------------------------------------------------------------------
__global__ __launch_bounds__(256) void norm_labels(const float* __restrict__ le,
                                                   float* __restrict__ leT) {
    __shared__ float red[L][4];
    __shared__ float rn[L];
    const int tid = threadIdx.x;
    const int wid = tid >> 6, lane = tid & 63;

    float acc[L] = {0.f, 0.f, 0.f};
    for (int h = tid; h < H; h += 256) {
        #pragma unroll
        for (int l = 0; l < L; ++l) {
            float v = le[h * L + l];
            acc[l] += v * v;
        }
    }
    #pragma unroll
    for (int l = 0; l < L; ++l) {
        float s = wave_reduce_sum(acc[l]);
        if (lane == 0) red[l][wid] = s;
    }
    __syncthreads();
    if (tid < L) {
        float s = red[tid][0] + red[tid][1] + red[tid][2] + red[tid][3];
        rn[tid] = 1.0f / fmaxf(sqrtf(s), NEPS);
    }
    __syncthreads();
    for (int h = tid; h < H; h += 256) {
        #pragma unroll
        for (int l = 0; l < L; ++l)
            leT[l * H + h] = le[h * L + l] * rn[l];
    }
}

// ---------------------------------------------------------------------------
// Kernel 2: one block per (b,s) row.  Stream the 1024-float row once,
// compute sum(x^2) and 3 dots against normalized labels, write
// atten[row][l] = dot_l / max(||x||,eps) + 10000*(mask-1).
// ---------------------------------------------------------------------------
__global__ __launch_bounds__(256) void row_kernel(const float* __restrict__ df,
                                                  const float* __restrict__ leT,
                                                  const float* __restrict__ mask,
                                                  float* __restrict__ atten) {
    const int row = blockIdx.x;          // b*S + s
    const int tid = threadIdx.x;
    const int wid = tid >> 6, lane = tid & 63;

    const float4 d  = *(const float4*)(df  + (size_t)row * H + tid * 4);
    const float4 l0 = *(const float4*)(leT + 0 * H + tid * 4);
    const float4 l1 = *(const float4*)(leT + 1 * H + tid * 4);
    const float4 l2 = *(const float4*)(leT + 2 * H + tid * 4);

    float ssq = d.x * d.x + d.y * d.y + d.z * d.z + d.w * d.w;
    float d0  = d.x * l0.x + d.y * l0.y + d.z * l0.z + d.w * l0.w;
    float d1  = d.x * l1.x + d.y * l1.y + d.z * l1.z + d.w * l1.w;
    float d2  = d.x * l2.x + d.y * l2.y + d.z * l2.z + d.w * l2.w;

    __shared__ float red[4][4];
    ssq = wave_reduce_sum(ssq);
    d0  = wave_reduce_sum(d0);
    d1  = wave_reduce_sum(d1);
    d2  = wave_reduce_sum(d2);
    if (lane == 0) {
        red[0][wid] = ssq; red[1][wid] = d0; red[2][wid] = d1; red[3][wid] = d2;
    }
    __syncthreads();
    if (tid == 0) {
        float tssq = red[0][0] + red[0][1] + red[0][2] + red[0][3];
        float td0  = red[1][0] + red[1][1] + red[1][2] + red[1][3];
        float td1  = red[2][0] + red[2][1] + red[2][2] + red[2][3];
        float td2  = red[3][0] + red[3][1] + red[3][2] + red[3][3];
        float rnrm = 1.0f / fmaxf(sqrtf(tssq), NEPS);
        float bias = 10000.0f * (mask[row] - 1.0f);
        float* o = atten + (size_t)row * L;
        o[0] = td0 * rnrm + bias;
        o[1] = td1 * rnrm + bias;
        o[2] = td2 * rnrm + bias;
    }
}

// ---------------------------------------------------------------------------
// Kernel 3: per batch b — pooled[s] = max over L of atten[b][s][:],
// normalized = softmax over S.  One block per b, 256 threads, 4 s each.
// ---------------------------------------------------------------------------
__global__ __launch_bounds__(256) void softmax_kernel(const float* __restrict__ atten,
                                                      float* __restrict__ norm) {
    const int b = blockIdx.x;
    const int tid = threadIdx.x;
    const int wid = tid >> 6, lane = tid & 63;

    float p[4];
    float m = -INFINITY;
    #pragma unroll
    for (int i = 0; i < 4; ++i) {
        int s = i * 256 + tid;
        const float* a = atten + ((size_t)b * S + s) * L;
        p[i] = fmaxf(fmaxf(a[0], a[1]), a[2]);
        m = fmaxf(m, p[i]);
    }
    __shared__ float redm[4];
    __shared__ float reds[4];
    __shared__ float bm, bsum;
    m = wave_reduce_max(m);
    if (lane == 0) redm[wid] = m;
    __syncthreads();
    if (tid == 0)
        bm = fmaxf(fmaxf(redm[0], redm[1]), fmaxf(redm[2], redm[3]));
    __syncthreads();
    float mm = bm;
    float e[4], ssum = 0.f;
    #pragma unroll
    for (int i = 0; i < 4; ++i) {
        e[i] = expf(p[i] - mm);
        ssum += e[i];
    }
    ssum = wave_reduce_sum(ssum);
    if (lane == 0) reds[wid] = ssum;
    __syncthreads();
    if (tid == 0) bsum = reds[0] + reds[1] + reds[2] + reds[3];
    __syncthreads();
    float rs = 1.0f / bsum;
    #pragma unroll
    for (int i = 0; i < 4; ++i) {
        int s = i * 256 + tid;
        norm[(size_t)b * S + s] = e[i] * rs;
    }
}

// ---------------------------------------------------------------------------
// Kernel 4: feature_attention[b][h] = sum_s norm[b][s] * df[b][s][h].
// Grid (S/SCHUNK, B); each block handles one s-chunk over full H,
// accumulates in registers, atomicAdds into zeroed output.
// ---------------------------------------------------------------------------
constexpr int SCHUNK = 64;
__global__ __launch_bounds__(256) void weighted_sum(const float* __restrict__ df,
                                                    const float* __restrict__ norm,
                                                    float* __restrict__ fa) {
    const int c = blockIdx.x;   // s chunk
    const int b = blockIdx.y;
    const int tid = threadIdx.x;

    __shared__ float w[SCHUNK];
    if (tid < SCHUNK) w[tid] = norm[(size_t)b * S + c * SCHUNK + tid];
    __syncthreads();

    const float* base = df + ((size_t)b * S + (size_t)c * SCHUNK) * H + tid * 4;
    float4 acc = make_float4(0.f, 0.f, 0.f, 0.f);
    #pragma unroll 4
    for (int i = 0; i < SCHUNK; ++i) {
        float4 d = *(const float4*)(base + (size_t)i * H);
        float ww = w[i];
        acc.x += ww * d.x;
        acc.y += ww * d.y;
        acc.z += ww * d.z;
        acc.w += ww * d.w;
    }
    float* o = fa + (size_t)b * H + tid * 4;
    atomicAdd(o + 0, acc.x);
    atomicAdd(o + 1, acc.y);
    atomicAdd(o + 2, acc.z);
    atomicAdd(o + 3, acc.w);
}

// ---------------------------------------------------------------------------
extern "C" void kernel_launch(void* const* d_in, const int* in_sizes, int n_in,
                              void* d_out, int out_size, void* d_ws, size_t ws_size,
                              hipStream_t stream) {
    const float* df   = (const float*)d_in[0];  // [B,S,H]
    const float* le   = (const float*)d_in[1];  // [H,L]
    const float* mask = (const float*)d_in[2];  // [B,S]

    float* out   = (float*)d_out;
    float* fa    = out;                          // [B,H]        65536
    float* atten = out + (size_t)B * H;          // [B,S,L]      196608
    float* norm  = atten + (size_t)B * S * L;    // [B,1,S]      65536

    float* leT = (float*)d_ws;                   // [L,H] = 12288 floats

    // feature_attention accumulated via atomics -> must start at zero
    hipMemsetAsync(fa, 0, (size_t)B * H * sizeof(float), stream);

    norm_labels<<<1, 256, 0, stream>>>(le, leT);
    row_kernel<<<B * S, 256, 0, stream>>>(df, leT, mask, atten);
    softmax_kernel<<<B, 256, 0, stream>>>(atten, norm);
    weighted_sum<<<dim3(S / SCHUNK, B), 256, 0, stream>>>(df, norm, fa);
}